// Round 4
// baseline (347.802 us; speedup 1.0000x reference)
//
#include <hip/hip_runtime.h>
#include <hip/hip_bf16.h>

// CorrelationLayer: out[b,(dy+4)*9+(dx+4),h,w] = sum_c f1[b,c,h,w]*f2[b,c,(h-dy)&63,(w-dx)&127]
// B=8 C=512 H=64 W=128.
//
// R3: overlap-focused restructure of the verified R2 math.
//  - TH=8 -> grid 512 = 8b x 8ht x 8wt; 256 thr = 4 waves, wave owns 2 h-rows.
//  - CC=32 (1 MFMA k-step/stage, 16 stages), double-buffered LDS:
//    2 x [16 rows][32 w][40c-pad] shorts = 80 KB -> 2 blocks/CU (was 1).
//  - Pipeline per stage: cvt A (prefetched) -> compute(cur) -> prefetch A(st+1)
//    + stage(st+1 -> other buf) -> barrier. Co-resident block covers the
//    exposed staging latency.
//  - B-frag ds_read_b128 banks: (20*lw + 4*lg) mod 32 -> exact 2-way (free).

typedef short  bf16x8  __attribute__((ext_vector_type(8)));
typedef short  short4v __attribute__((ext_vector_type(4)));
typedef float  f32x4   __attribute__((ext_vector_type(4)));

#define NC 512
#define NH 64
#define NW 128
#define HW (NH * NW)
#define TH 8
#define TW 16
#define CC 32                  // channels per stage = one 16x16x32 k-step
#define NST (NC / CC)          // 16
#define LROW 16                // TH + 8 halo rows
#define LCP 40                 // 32 c + 8 pad (shorts); keeps b128 16B-aligned
#define BUFS (LROW * 32 * LCP) // 20480 shorts = 40960 B per buffer

__device__ __forceinline__ short f2bf(float x) {
  union { __hip_bfloat16 h; short s; } u;
  u.h = __float2bfloat16(x);
  return u.s;
}

__global__ __launch_bounds__(256, 2)
void corr_mfma(const float* __restrict__ f1, const float* __restrict__ f2,
               float* __restrict__ out) {
  __shared__ short lds[2 * BUFS];

  const int t    = threadIdx.x;
  const int b    = blockIdx.x & 7;        // XCD pin: batch == XCD
  const int tile = blockIdx.x >> 3;       // 0..63
  const int h0   = (tile >> 3) * TH;      // 0,8,...,56
  const int w0   = (tile & 7) * TW;       // 0..112

  const int wv = t >> 6;                  // wave 0..3
  const int l  = t & 63;
  const int lg = l >> 4;                  // 0..3
  const int lw = l & 15;                  // 0..15

  // staging map: 256 thr = 32 w_local x 8 c-quads; r-loop covers 16 rows
  const int sw  = t & 31;                 // w_local 0..31
  const int scq = t >> 5;                 // c-quad 0..7 (c = 4*scq..+3)
  const int wg  = (w0 - 4 + sw) & (NW - 1);

  const float* f1b = f1 + b * NC * HW;
  const float* f2b = f2 + b * NC * HW;

  f32x4 acc[2][9][2];
#pragma unroll
  for (int hh = 0; hh < 2; ++hh)
#pragma unroll
    for (int d = 0; d < 9; ++d)
#pragma unroll
      for (int wt = 0; wt < 2; ++wt)
        acc[hh][d][wt] = (f32x4){0.f, 0.f, 0.f, 0.f};

  const int hA = h0 + 2 * wv;

  // ---- A prefetch registers (raw fp32, converted at consume time)
  float a_nxt[2][8];

  // prologue: A(0) + stage(0 -> buf0)
#pragma unroll
  for (int hh = 0; hh < 2; ++hh) {
    const float* s = f1b + (8 * lg) * HW + (hA + hh) * NW + (w0 + lw);
#pragma unroll
    for (int e = 0; e < 8; ++e) a_nxt[hh][e] = s[e * HW];
  }
  {
    const float* src = f2b + (4 * scq) * HW + wg;
    short* dst = lds + sw * LCP + 4 * scq;
#pragma unroll
    for (int r = 0; r < LROW; ++r) {
      const int h2 = (h0 - 4 + r) & (NH - 1);
      const float* s = src + h2 * NW;
      float x0 = s[0], x1 = s[HW], x2 = s[2 * HW], x3 = s[3 * HW];
      short4v v = { f2bf(x0), f2bf(x1), f2bf(x2), f2bf(x3) };
      *reinterpret_cast<short4v*>(dst + r * 32 * LCP) = v;
    }
  }
  __syncthreads();

  for (int st = 0; st < NST; ++st) {
    const int cur = st & 1;

    // consume prefetched A
    bf16x8 afr[2];
#pragma unroll
    for (int hh = 0; hh < 2; ++hh)
#pragma unroll
      for (int e = 0; e < 8; ++e)
        afr[hh][e] = f2bf(a_nxt[hh][e]);

    // compute on buf[cur]
    const short* bbase = lds + cur * BUFS;
#pragma unroll
    for (int ro = 0; ro < 10; ++ro) {
      const int row = 2 * wv + ro;
#pragma unroll
      for (int wt = 0; wt < 2; ++wt) {
        const bf16x8 bfr = *reinterpret_cast<const bf16x8*>(
            bbase + (row * 32 + 16 * wt + lw) * LCP + 8 * lg);
        if (ro <= 8)
          acc[0][8 - ro][wt] = __builtin_amdgcn_mfma_f32_16x16x32_bf16(
              afr[0], bfr, acc[0][8 - ro][wt], 0, 0, 0);
        if (ro >= 1)
          acc[1][9 - ro][wt] = __builtin_amdgcn_mfma_f32_16x16x32_bf16(
              afr[1], bfr, acc[1][9 - ro][wt], 0, 0, 0);
      }
    }

    // prefetch A(st+1) + stage(st+1) into the other buffer
    if (st + 1 < NST) {
      const int c0 = (st + 1) * CC;
#pragma unroll
      for (int hh = 0; hh < 2; ++hh) {
        const float* s = f1b + (c0 + 8 * lg) * HW + (hA + hh) * NW + (w0 + lw);
#pragma unroll
        for (int e = 0; e < 8; ++e) a_nxt[hh][e] = s[e * HW];
      }
      const float* src = f2b + (c0 + 4 * scq) * HW + wg;
      short* dst = lds + (1 - cur) * BUFS + sw * LCP + 4 * scq;
#pragma unroll
      for (int r = 0; r < LROW; ++r) {
        const int h2 = (h0 - 4 + r) & (NH - 1);
        const float* s = src + h2 * NW;
        float x0 = s[0], x1 = s[HW], x2 = s[2 * HW], x3 = s[3 * HW];
        short4v v = { f2bf(x0), f2bf(x1), f2bf(x2), f2bf(x3) };
        *reinterpret_cast<short4v*>(dst + r * 32 * LCP) = v;
      }
    }
    __syncthreads();
  }

  // ---- epilogue: D[p=4*lg+r][q=lw]; dxi = p - lw + 8 - 16*wt
#pragma unroll
  for (int hh = 0; hh < 2; ++hh) {
    const int h = hA + hh;
#pragma unroll
    for (int d = 0; d < 9; ++d) {
#pragma unroll
      for (int wt = 0; wt < 2; ++wt) {
#pragma unroll
        for (int r = 0; r < 4; ++r) {
          const int p   = 4 * lg + r;
          const int dxi = p - lw + (wt == 0 ? 8 : -8);
          if (dxi >= 0 && dxi <= 8) {
            out[((b * 81 + d * 9 + dxi) * NH + h) * NW + (w0 + p)] = acc[hh][d][wt][r];
          }
        }
      }
    }
  }
}

extern "C" void kernel_launch(void* const* d_in, const int* in_sizes, int n_in,
                              void* d_out, int out_size, void* d_ws, size_t ws_size,
                              hipStream_t stream) {
  const float* f1 = (const float*)d_in[0];
  const float* f2 = (const float*)d_in[1];
  float* out = (float*)d_out;
  corr_mfma<<<dim3(512), dim3(256), 0, stream>>>(f1, f2, out);
}